// Round 4
// baseline (61.687 us; speedup 1.0000x reference)
//
#include <hip/hip_runtime.h>
#include <math.h>
#include <stdint.h>

#define D_MODEL 128
#define EDGE_DIM 9
#define HIDDEN 256
#define BATCH 2
#define NN 512

#define ROWSN 8  // rows per block in kernel 1
#define TI 4     // i-tile in kernel 2
#define TJ 64    // j-tile in kernel 2

typedef _Float16 h2v __attribute__((ext_vector_type(2)));
typedef __fp16   fp16x2 __attribute__((ext_vector_type(2)));

__device__ __forceinline__ h2v relu2(h2v v) {
    h2v z = {(_Float16)0.0f, (_Float16)0.0f};
    return __builtin_elementwise_max(v, z);
}
__device__ __forceinline__ uint32_t h2u(h2v v) { return __builtin_bit_cast(uint32_t, v); }
__device__ __forceinline__ h2v u2h(uint32_t u) { return __builtin_bit_cast(h2v, u); }
__device__ __forceinline__ h2v pkrtz(float a, float b) {
    return __builtin_bit_cast(h2v, __builtin_amdgcn_cvt_pkrtz(a, b));
}
__device__ __forceinline__ float fdot2(h2v a, h2v b, float c) {
    return __builtin_amdgcn_fdot2(__builtin_bit_cast(fp16x2, a),
                                  __builtin_bit_cast(fp16x2, b), c, false);
}

// ---------------------------------------------------------------------------
// Kernel 1: pi = f16(z@We_i + be1), pj = f16(z@We_j), organ head in f32.
// 512 threads = 8 waves; wave w owns row r0+w; lane l owns h = 4l..4l+3.
// Weights loaded as float4 (L1 broadcasts across the 8 row-waves).
// Organ reduce: pure-register 64-lane shfl tree per wave.
// ---------------------------------------------------------------------------
__global__ __launch_bounds__(512) void node_proj_kernel(
    const float* __restrict__ z,      // (B*N, 128)
    const float* __restrict__ Wo1,    // (128,256)
    const float* __restrict__ bo1,    // (256)
    const float* __restrict__ Wo2,    // (256,1)
    const float* __restrict__ bo2,    // (1)
    const float* __restrict__ We_i,   // (128,256)
    const float* __restrict__ We_j,   // (128,256)
    const float* __restrict__ be1,    // (256)
    float* __restrict__ organ_out,    // (B*N)
    uint32_t* __restrict__ pi_h,      // (B*N,128) half2, includes +be1
    uint32_t* __restrict__ pj_h)      // (B*N,128) half2
{
    __shared__ float z_s[ROWSN][D_MODEL];

    const int t  = threadIdx.x;
    const int r0 = blockIdx.x * ROWSN;

    // stage ROWSN*128 = 1024 floats with 512 threads
#pragma unroll
    for (int k = 0; k < 2; ++k) {
        const int idx = t + k * 512;
        z_s[idx >> 7][idx & 127] = z[r0 * D_MODEL + idx];
    }
    __syncthreads();

    const int w = t >> 6;   // row within tile
    const int l = t & 63;   // h-group: h = 4l..4l+3

    float4 accO = ((const float4*)bo1)[l];
    float4 accI = ((const float4*)be1)[l];
    float4 accJ = {0.f, 0.f, 0.f, 0.f};

    const float* zr = &z_s[w][0];

#pragma unroll 4
    for (int d = 0; d < D_MODEL; ++d) {
        const float4 w1 = ((const float4*)Wo1 )[d * 64 + l];
        const float4 wi = ((const float4*)We_i)[d * 64 + l];
        const float4 wj = ((const float4*)We_j)[d * 64 + l];
        const float zv = zr[d];
        accO.x = fmaf(zv, w1.x, accO.x); accO.y = fmaf(zv, w1.y, accO.y);
        accO.z = fmaf(zv, w1.z, accO.z); accO.w = fmaf(zv, w1.w, accO.w);
        accI.x = fmaf(zv, wi.x, accI.x); accI.y = fmaf(zv, wi.y, accI.y);
        accI.z = fmaf(zv, wi.z, accI.z); accI.w = fmaf(zv, wi.w, accI.w);
        accJ.x = fmaf(zv, wj.x, accJ.x); accJ.y = fmaf(zv, wj.y, accJ.y);
        accJ.z = fmaf(zv, wj.z, accJ.z); accJ.w = fmaf(zv, wj.w, accJ.w);
    }

    // organ head (f32): v = relu(accO) . Wo2[4l..4l+3], wave tree reduce
    const float4 wo2 = ((const float4*)Wo2)[l];
    float v = fmaf(fmaxf(accO.x, 0.f), wo2.x,
              fmaf(fmaxf(accO.y, 0.f), wo2.y,
              fmaf(fmaxf(accO.z, 0.f), wo2.z,
                   fmaxf(accO.w, 0.f) * wo2.w)));
#pragma unroll
    for (int s = 1; s <= 32; s <<= 1) v += __shfl_xor(v, s, 64);
    if (l == 0) {
        const float s = v + bo2[0];
        organ_out[r0 + w] = 1.f / (1.f + expf(-s));
    }

    // pi/pj in packed f16
    const size_t row = (size_t)(r0 + w);
    uint2 upi, upj;
    upi.x = h2u(pkrtz(accI.x, accI.y));
    upi.y = h2u(pkrtz(accI.z, accI.w));
    upj.x = h2u(pkrtz(accJ.x, accJ.y));
    upj.y = h2u(pkrtz(accJ.z, accJ.w));
    *(uint2*)&pi_h[row * 128 + 2 * l] = upi;
    *(uint2*)&pj_h[row * 128 + 2 * l] = upj;
}

// ---------------------------------------------------------------------------
// Kernel 2: fused edge head, packed-f16 inner math, f32 dot accumulation.
// grid = 1024 blocks, 512 threads = 8 waves. Wave w handles jl = w*8+q.
// Lane owns h = 4*lane (2 half2). E staged in LDS as duplicated half2
// (padded 9->12, rows 48B so uint4-aligned). v_dot2_f32_f16 for the We2 dot.
// Paired-batch butterfly reduce; one-output-per-thread epilogue.
// ---------------------------------------------------------------------------
__global__ __launch_bounds__(512, 4) void edge_kernel(
    const float* __restrict__ E,      // (N,N,9)
    const int*   __restrict__ mask,   // (N,N)
    const float* __restrict__ We_e,   // (9,256)
    const float* __restrict__ We2,    // (256,1)
    const float* __restrict__ be2,    // (1)
    const uint32_t* __restrict__ pi_h,  // (B*N,128) half2
    const uint32_t* __restrict__ pj_h,  // (B*N,128) half2
    float* __restrict__ edge_out)     // (B,N,N)
{
    __shared__ __align__(16) uint32_t E_s[TI][TJ][12];  // dup'd half2, 12 KiB
    __shared__ float sums_s[BATCH][TI][TJ];             // 2 KiB

    const int t    = threadIdx.x;
    const int lane = t & 63;
    const int wave = t >> 6;
    const int bi   = blockIdx.x;
    const int i0   = (bi >> 3) * TI;   // 128 i-blocks
    const int j0   = (bi & 7) * TJ;    // 8 j-blocks

    // Stage E tile as duplicated f16 pairs (value in both halves).
#pragma unroll
    for (int ii = 0; ii < TI; ++ii) {
        const float* src = &E[((size_t)(i0 + ii) * NN + j0) * EDGE_DIM];
        for (int idx = t; idx < TJ * EDGE_DIM; idx += 512) {
            const int jl = idx / 9;
            const int d  = idx - jl * 9;
            const float e = src[idx];
            E_s[ii][jl][d] = h2u(pkrtz(e, e));
        }
    }

    // Per-lane weights in f16: h = 4*lane + {0,1} | {2,3}
    h2v wee[EDGE_DIM][2];
    const float4* We_e4 = (const float4*)We_e;
#pragma unroll
    for (int d = 0; d < EDGE_DIM; ++d) {
        const float4 w = We_e4[d * 64 + lane];
        wee[d][0] = pkrtz(w.x, w.y);
        wee[d][1] = pkrtz(w.z, w.w);
    }
    h2v w2[2];
    {
        const float4 w = ((const float4*)We2)[lane];
        w2[0] = pkrtz(w.x, w.y);
        w2[1] = pkrtz(w.z, w.w);
    }

    h2v pir[BATCH][TI][2];
#pragma unroll
    for (int b = 0; b < BATCH; ++b)
#pragma unroll
        for (int ii = 0; ii < TI; ++ii) {
            const uint2 u = ((const uint2*)&pi_h[(size_t)(b * NN + i0 + ii) * 128])[lane];
            pir[b][ii][0] = u2h(u.x);
            pir[b][ii][1] = u2h(u.y);
        }

    __syncthreads();

#pragma unroll
    for (int q = 0; q < 8; ++q) {
        const int jl = wave * 8 + q;
        const int j  = j0 + jl;
        h2v pjr[BATCH][2];
#pragma unroll
        for (int b = 0; b < BATCH; ++b) {
            const uint2 u = ((const uint2*)&pj_h[(size_t)(b * NN + j) * 128])[lane];
            pjr[b][0] = u2h(u.x);
            pjr[b][1] = u2h(u.y);
        }

#pragma unroll
        for (int ii = 0; ii < TI; ++ii) {
            // 9 dup'd E values: 2x b128 + 1x b32 broadcast reads
            const uint4* ep = (const uint4*)&E_s[ii][jl][0];
            const uint4 ua = ep[0];
            const uint4 ub = ep[1];
            const uint32_t uc = ((const uint32_t*)ep)[8];

            h2v pe0, pe1;
            {
                const h2v e0 = u2h(ua.x), e1 = u2h(ua.y), e2 = u2h(ua.z), e3 = u2h(ua.w);
                const h2v e4 = u2h(ub.x), e5 = u2h(ub.y), e6 = u2h(ub.z), e7 = u2h(ub.w);
                const h2v e8 = u2h(uc);
                pe0 = e0 * wee[0][0];            pe1 = e0 * wee[0][1];
                pe0 = pe0 + e1 * wee[1][0];      pe1 = pe1 + e1 * wee[1][1];
                pe0 = pe0 + e2 * wee[2][0];      pe1 = pe1 + e2 * wee[2][1];
                pe0 = pe0 + e3 * wee[3][0];      pe1 = pe1 + e3 * wee[3][1];
                pe0 = pe0 + e4 * wee[4][0];      pe1 = pe1 + e4 * wee[4][1];
                pe0 = pe0 + e5 * wee[5][0];      pe1 = pe1 + e5 * wee[5][1];
                pe0 = pe0 + e6 * wee[6][0];      pe1 = pe1 + e6 * wee[6][1];
                pe0 = pe0 + e7 * wee[7][0];      pe1 = pe1 + e7 * wee[7][1];
                pe0 = pe0 + e8 * wee[8][0];      pe1 = pe1 + e8 * wee[8][1];
            }

            float acc[BATCH];
#pragma unroll
            for (int b = 0; b < BATCH; ++b) {
                h2v v0 = relu2(pir[b][ii][0] + pjr[b][0] + pe0);
                h2v v1 = relu2(pir[b][ii][1] + pjr[b][1] + pe1);
                acc[b] = fdot2(v1, w2[1], fdot2(v0, w2[0], 0.f));
            }

            // paired butterfly: even lanes -> b=0 sum, odd lanes -> b=1 sum
            float r  = (lane & 1) ? acc[1] : acc[0];
            float o_ = (lane & 1) ? acc[0] : acc[1];
            r += __shfl_xor(o_, 1, 64);
#pragma unroll
            for (int s = 2; s <= 32; s <<= 1) r += __shfl_xor(r, s, 64);
            if (lane < 2) sums_s[lane][ii][jl] = r;
        }
    }
    __syncthreads();

    // Epilogue: one output per thread (512 = BATCH*TI*TJ).
    {
        const int b   = t >> 8;
        const int rem = t & 255;
        const int ii  = rem >> 6;
        const int jl  = rem & 63;
        const int i = i0 + ii, j = j0 + jl;
        const float s = sums_s[b][ii][jl] + be2[0];
        float p = 1.f / (1.f + expf(-s));
        p *= (float)mask[i * NN + j];
        edge_out[((size_t)b * NN + i) * NN + j] = p;
    }
}

extern "C" void kernel_launch(void* const* d_in, const int* in_sizes, int n_in,
                              void* d_out, int out_size, void* d_ws, size_t ws_size,
                              hipStream_t stream) {
    const float* z    = (const float*)d_in[0];   // (B,N,128)
    const float* E    = (const float*)d_in[1];   // (N,N,9)
    const int*   mask = (const int*)  d_in[2];   // (N,N)
    const float* Wo1  = (const float*)d_in[3];
    const float* bo1  = (const float*)d_in[4];
    const float* Wo2  = (const float*)d_in[5];
    const float* bo2  = (const float*)d_in[6];
    const float* We_i = (const float*)d_in[7];
    const float* We_j = (const float*)d_in[8];
    const float* We_e = (const float*)d_in[9];
    const float* be1  = (const float*)d_in[10];
    const float* We2  = (const float*)d_in[11];
    const float* be2  = (const float*)d_in[12];

    float* out_organ = (float*)d_out;                 // (B,N) = 1024
    float* out_edge  = out_organ + BATCH * NN;        // (B,N,N)

    uint32_t* pi_h = (uint32_t*)d_ws;                        // (B*N,128) half2
    uint32_t* pj_h = pi_h + (size_t)BATCH * NN * (HIDDEN/2); // (B*N,128) half2

    hipLaunchKernelGGL(node_proj_kernel,
                       dim3((BATCH * NN) / ROWSN), dim3(512), 0, stream,
                       z, Wo1, bo1, Wo2, bo2, We_i, We_j, be1,
                       out_organ, pi_h, pj_h);

    hipLaunchKernelGGL(edge_kernel,
                       dim3((NN / TI) * (NN / TJ)), dim3(512), 0, stream,
                       E, mask, We_e, We2, be2, pi_h, pj_h, out_edge);
}